// Round 12
// baseline (294.186 us; speedup 1.0000x reference)
//
#include <hip/hip_runtime.h>
#include <math.h>

#define T_DIM 256
#define B_DIM 32
#define N_DIM 64
#define F_INF 1024
#define D_T 272
#define D_TP 288   // K-padded row stride for 272-wide activations
#define H_DIM 8
#define DH_DIM 34
#define DFF_DIM 1024

typedef unsigned int uint;
typedef short bf16x8 __attribute__((ext_vector_type(8)));
typedef float f32x4 __attribute__((ext_vector_type(4)));

__device__ __forceinline__ ushort f2bf(float f) {
    uint u = __float_as_uint(f);
    uint r = (u + 0x7fffu + ((u >> 16) & 1u)) >> 16;
    return (ushort)r;
}
__device__ __forceinline__ float bf2f(ushort u) {
    return __uint_as_float(((uint)u) << 16);
}

// ---------------------------------------------------------------------------
// merged wconv (tiled f32 [K,N] -> bf16 [N,Kp]) + init (xn elementwise +
// one-time pad zeroing). Blocks < ntiles do wconv; rest do init elements.
// ---------------------------------------------------------------------------
struct WT {
    int tstart[11];
    const float* src[10];
    ushort* dst[10];
    int N[10];
    int Kp[10];
    int ntn[10];  // N/16
};
struct PadPtrs {
    uint* wt[6];
    int nrows[6];
};
__global__ __launch_bounds__(256) void wconv_init(WT s, int ntiles,
                                                  const float* __restrict__ x,
                                                  const float* __restrict__ Ru,
                                                  ushort* __restrict__ xn,
                                                  uint* __restrict__ qkvb,
                                                  uint* __restrict__ x1,
                                                  uint* __restrict__ attno, PadPtrs p) {
    __shared__ float t[16][17];
    if ((int)blockIdx.x < ntiles) {
        int tile = blockIdx.x;
        int seg = 0;
        while (seg < 9 && tile >= s.tstart[seg + 1]) ++seg;
        int ti = tile - s.tstart[seg];
        int ntn = s.ntn[seg];
        int tk = ti / ntn, tn = ti - tk * ntn;
        int N = s.N[seg], Kp = s.Kp[seg];
        int ty = threadIdx.x >> 4, tx = threadIdx.x & 15;
        t[ty][tx] = s.src[seg][(size_t)(tk * 16 + ty) * N + tn * 16 + tx];
        __syncthreads();
        s.dst[seg][(size_t)(tn * 16 + ty) * Kp + tk * 16 + tx] = f2bf(t[tx][ty]);
        return;
    }
    const int TB = T_DIM * B_DIM;
    const int NXN = B_DIM * N_DIM * F_INF;
    int idx = (blockIdx.x - ntiles) * 256 + threadIdx.x;
    if (idx < NXN) {
        int f = idx & 1023;
        int bn = idx >> 10;
        int n = bn & 63;
        int b = bn >> 6;
        int tt = f >> 2;
        int d = f & 3;
        float v = x[(tt * B_DIM + b) * N_DIM + n] * Ru[(n << 2) + d];
        xn[idx] = f2bf(fmaxf(v, 0.0f));
        return;
    }
    idx -= NXN;
    if (idx < TB * 8) {
        int row = idx >> 3, q = idx & 7;
        x1[(size_t)row * 144 + 136 + q] = 0;
        attno[(size_t)row * 144 + 136 + q] = 0;
        return;
    }
    idx -= TB * 8;
    if (idx < TB * 72) {
        int row = idx / 72;
        int r = idx - row * 72;
        int g = r / 3, q = r - g * 3;
        qkvb[(size_t)row * 480 + g * 20 + 17 + q] = 0;
        return;
    }
    idx -= TB * 72;
#pragma unroll
    for (int sgi = 0; sgi < 6; ++sgi) {
        int cnt = p.nrows[sgi] * 8;
        if (idx < cnt) {
            int row = idx >> 3, q = idx & 7;
            p.wt[sgi][(size_t)row * 144 + 136 + q] = 0;
            return;
        }
        idx -= cnt;
    }
}

// ---------------------------------------------------------------------------
// MFMA bf16 GEMM, 3-deep ring, counted vmcnt (validated round 8).
// BM=64, BN=128, BK=32; 256 thr = 4 waves (2x2), wave tile 32x64.
// OUT_MODE: 1 bf16 flat, 2 bf16 head-padded QKV,
//           3 f32 split-K partial, 4 prop1-fused row-reduce -> s1 bf16.
// ---------------------------------------------------------------------------
template <int ACT, int OUT_MODE>
__global__ __launch_bounds__(256) void gemm_mfma(const ushort* __restrict__ A,
                                                 const ushort* __restrict__ Bt,
                                                 const float* __restrict__ bias,
                                                 void* __restrict__ Cout,
                                                 int M, int N, int K, int Kstride) {
    __shared__ ushort As[3][64 * 32];
    __shared__ ushort Bs[3][128 * 32];
    const int tid = threadIdx.x;
    const int m0 = (OUT_MODE == 3) ? 0 : blockIdx.y * 64;
    const int n0 = blockIdx.x * 128;
    if (OUT_MODE == 3) {
        A += (size_t)blockIdx.y * K;
        Bt += (size_t)blockIdx.y * K;
    }
    const int w = tid >> 6, lane = tid & 63;
    const int wr = w >> 1, wc = w & 1;
    const int lr = lane & 15, lk = lane >> 4;

    const int ns = K >> 5;

    const int ra = w * 16 + (lane >> 2);
    const int ca = (((lane & 3) ^ ((ra >> 1) & 3)) << 3);
    int gma = m0 + ra; if (gma > M - 1) gma = M - 1;
    const ushort* gA = &A[(size_t)gma * Kstride + ca];
    const int rb0 = w * 32 + (lane >> 2);
    const int cb0 = (((lane & 3) ^ ((rb0 >> 1) & 3)) << 3);
    const int rb1 = rb0 + 16;
    const int cb1 = (((lane & 3) ^ ((rb1 >> 1) & 3)) << 3);
    int gnb0 = n0 + rb0; if (gnb0 > N - 1) gnb0 = N - 1;
    int gnb1 = n0 + rb1; if (gnb1 > N - 1) gnb1 = N - 1;
    const ushort* gB0 = &Bt[(size_t)gnb0 * Kstride + cb0];
    const ushort* gB1 = &Bt[(size_t)gnb1 * Kstride + cb1];

    f32x4 acc[2][4];
#pragma unroll
    for (int i = 0; i < 2; ++i)
#pragma unroll
        for (int j = 0; j < 4; ++j) acc[i][j] = (f32x4){0.f, 0.f, 0.f, 0.f};

    auto stage = [&](int buf, int s) {
        const int k0 = s << 5;
        __builtin_amdgcn_global_load_lds(
            (const __attribute__((address_space(1))) void*)(gA + k0),
            (__attribute__((address_space(3))) void*)(&As[buf][w * 512]), 16, 0, 0);
        __builtin_amdgcn_global_load_lds(
            (const __attribute__((address_space(1))) void*)(gB0 + k0),
            (__attribute__((address_space(3))) void*)(&Bs[buf][w * 1024]), 16, 0, 0);
        __builtin_amdgcn_global_load_lds(
            (const __attribute__((address_space(1))) void*)(gB1 + k0),
            (__attribute__((address_space(3))) void*)(&Bs[buf][w * 1024 + 512]), 16, 0, 0);
    };

    stage(0, 0);
    stage(1, 1);
    asm volatile("s_waitcnt vmcnt(3)" ::: "memory");
    __builtin_amdgcn_sched_barrier(0);
    __builtin_amdgcn_s_barrier();
    __builtin_amdgcn_sched_barrier(0);

    int cur = 0;
    for (int s = 0; s < ns; ++s) {
        int stg = cur + 2; if (stg >= 3) stg -= 3;
        if (s + 2 < ns) stage(stg, s + 2);

        bf16x8 af[2], bf[4];
#pragma unroll
        for (int mt = 0; mt < 2; ++mt) {
            int row = wr * 32 + mt * 16 + lr;
            int ch = lk ^ ((row >> 1) & 3);
            af[mt] = *reinterpret_cast<const bf16x8*>(&As[cur][row * 32 + ch * 8]);
        }
#pragma unroll
        for (int nt = 0; nt < 4; ++nt) {
            int row = wc * 64 + nt * 16 + lr;
            int ch = lk ^ ((row >> 1) & 3);
            bf[nt] = *reinterpret_cast<const bf16x8*>(&Bs[cur][row * 32 + ch * 8]);
        }
        __builtin_amdgcn_s_setprio(1);
#pragma unroll
        for (int mt = 0; mt < 2; ++mt)
#pragma unroll
            for (int nt = 0; nt < 4; ++nt)
                acc[mt][nt] = __builtin_amdgcn_mfma_f32_16x16x32_bf16(
                    af[mt], bf[nt], acc[mt][nt], 0, 0, 0);
        __builtin_amdgcn_s_setprio(0);

        if (s + 1 < ns) {
            if (s + 2 < ns)
                asm volatile("s_waitcnt vmcnt(3)" ::: "memory");
            else
                asm volatile("s_waitcnt vmcnt(0)" ::: "memory");
            __builtin_amdgcn_sched_barrier(0);
            __builtin_amdgcn_s_barrier();
            __builtin_amdgcn_sched_barrier(0);
        }
        cur = (cur == 2) ? 0 : cur + 1;
    }

    if (OUT_MODE == 4) {
        __shared__ float red[2][128];
        float part[4];
#pragma unroll
        for (int nt = 0; nt < 4; ++nt) {
            int col = n0 + wc * 64 + nt * 16 + lr;
            float bv = bias[col];
            float s = 0.f;
#pragma unroll
            for (int mt = 0; mt < 2; ++mt)
#pragma unroll
                for (int r = 0; r < 4; ++r) s += fmaxf(acc[mt][nt][r] + bv, 0.f);
            s += __shfl_xor(s, 16);
            s += __shfl_xor(s, 32);
            part[nt] = s;
        }
        if (lk == 0) {
#pragma unroll
            for (int nt = 0; nt < 4; ++nt) red[wr][wc * 64 + nt * 16 + lr] = part[nt];
        }
        __syncthreads();
        if (tid < 128) {
            float tot = red[0][tid] + red[1][tid];
            ((ushort*)Cout)[(size_t)blockIdx.y * 1024 + n0 + tid] =
                f2bf(tot * (1.0f / 64.0f));
        }
        return;
    }

#pragma unroll
    for (int nt = 0; nt < 4; ++nt) {
        int col = n0 + wc * 64 + nt * 16 + lr;
        if (col >= N) continue;
        float bv = (OUT_MODE == 3) ? 0.f : bias[col];
        int g = 0, dcol = 0;
        if (OUT_MODE == 2) { g = col / 34; dcol = col - g * 34; }
#pragma unroll
        for (int mt = 0; mt < 2; ++mt) {
#pragma unroll
            for (int r = 0; r < 4; ++r) {
                int row = m0 + wr * 32 + mt * 16 + lk * 4 + r;
                if (row >= M) continue;
                float v = acc[mt][nt][r] + bv;
                if (ACT == 1) v = fmaxf(v, 0.0f);
                if (OUT_MODE == 1)
                    ((ushort*)Cout)[(size_t)row * N + col] = f2bf(v);
                else if (OUT_MODE == 2)
                    ((ushort*)Cout)[(size_t)row * 960 + g * 40 + dcol] = f2bf(v);
                else
                    ((float*)Cout)[(size_t)(blockIdx.y * M + row) * N + col] = v;
            }
        }
    }
}

// ---------------------------------------------------------------------------
// Fused GEMM+resid+LN (phase A, N=272) THEN FFN1 (phase B, N=1024) for the
// same 64 rows. Phase A: x1 = LN(resid + A@Bt + bias)*lnw+lnb (written to
// global AND kept in LDS y, stride 296). Phase B: h1 = relu(y @ B2t + bias2)
// looped over 8 N-chunks of 128, 3-ring B staging, counted vmcnt(2).
// ---------------------------------------------------------------------------
#define YSTR 296
#define RING 19456
__global__ __launch_bounds__(256) void gemm_ln_ffn(const ushort* __restrict__ A,
                                                   const ushort* __restrict__ Bt,
                                                   const float* __restrict__ bias,
                                                   const ushort* __restrict__ resid,
                                                   const float* __restrict__ lnw,
                                                   const float* __restrict__ lnb,
                                                   ushort* __restrict__ X1out,
                                                   const ushort* __restrict__ B2t,
                                                   const float* __restrict__ bias2,
                                                   ushort* __restrict__ H1out) {
    __shared__ ushort lds[32256];  // A: As 3x2048 @0, Bs 3x8704 @6144
    const int tid = threadIdx.x;
    const int m0 = blockIdx.x * 64;
    const int w = tid >> 6, lane = tid & 63;
    const int lr = lane & 15, lk = lane >> 4;
    const int ns = 9;  // K = 288

    // ================= phase A =================
    {
        const int ra = w * 16 + (lane >> 2);
        const int ca = (((lane & 3) ^ ((ra >> 1) & 3)) << 3);
        const ushort* gA = &A[(size_t)(m0 + ra) * D_TP + ca];

        f32x4 acc[17];
#pragma unroll
        for (int t = 0; t < 17; ++t) acc[t] = (f32x4){0.f, 0.f, 0.f, 0.f};

        auto stage = [&](int buf, int s) {
            const int k0 = s << 5;
            __builtin_amdgcn_global_load_lds(
                (const __attribute__((address_space(1))) void*)(gA + k0),
                (__attribute__((address_space(3))) void*)(&lds[buf * 2048 + w * 512]),
                16, 0, 0);
            for (int c = w; c < 17; c += 4) {
                int row16 = c * 16 + (lane >> 2);
                int p8 = (((lane & 3) ^ ((row16 >> 1) & 3)) << 3);
                const ushort* src = &Bt[(size_t)row16 * D_TP + k0 + p8];
                __builtin_amdgcn_global_load_lds(
                    (const __attribute__((address_space(1))) void*)src,
                    (__attribute__((address_space(3))) void*)(&lds[6144 + buf * 8704 + c * 512]),
                    16, 0, 0);
            }
        };

        stage(0, 0);
        stage(1, 1);
        if (w == 0)
            asm volatile("s_waitcnt vmcnt(6)" ::: "memory");
        else
            asm volatile("s_waitcnt vmcnt(5)" ::: "memory");
        __builtin_amdgcn_sched_barrier(0);
        __builtin_amdgcn_s_barrier();
        __builtin_amdgcn_sched_barrier(0);

        int cur = 0;
        for (int s = 0; s < ns; ++s) {
            int stg = cur + 2; if (stg >= 3) stg -= 3;
            if (s + 2 < ns) stage(stg, s + 2);

            bf16x8 af;
            {
                int row = w * 16 + lr;
                int ch = lk ^ ((row >> 1) & 3);
                af = *reinterpret_cast<const bf16x8*>(&lds[cur * 2048 + row * 32 + ch * 8]);
            }
            __builtin_amdgcn_s_setprio(1);
#pragma unroll
            for (int t = 0; t < 17; ++t) {
                int row = t * 16 + lr;
                int ch = lk ^ ((row >> 1) & 3);
                bf16x8 bf = *reinterpret_cast<const bf16x8*>(
                    &lds[6144 + cur * 8704 + row * 32 + ch * 8]);
                acc[t] = __builtin_amdgcn_mfma_f32_16x16x32_bf16(af, bf, acc[t], 0, 0, 0);
            }
            __builtin_amdgcn_s_setprio(0);

            if (s + 1 < ns) {
                if (s + 2 < ns) {
                    if (w == 0)
                        asm volatile("s_waitcnt vmcnt(6)" ::: "memory");
                    else
                        asm volatile("s_waitcnt vmcnt(5)" ::: "memory");
                } else {
                    asm volatile("s_waitcnt vmcnt(0)" ::: "memory");
                }
                __builtin_amdgcn_sched_barrier(0);
                __builtin_amdgcn_s_barrier();
                __builtin_amdgcn_sched_barrier(0);
            }
            cur = (cur == 2) ? 0 : cur + 1;
        }

        // epilogue: residual + LN
        __syncthreads();
        for (int i = tid; i < 64 * 34; i += 256) {
            int row = i / 34, c8 = i - row * 34;
            *reinterpret_cast<uint4*>(&lds[row * 272 + c8 * 8]) =
                *reinterpret_cast<const uint4*>(&resid[(size_t)(m0 + row) * D_TP + c8 * 8]);
        }
        __syncthreads();

        float sum[4] = {0.f, 0.f, 0.f, 0.f}, sq[4] = {0.f, 0.f, 0.f, 0.f};
#pragma unroll
        for (int t = 0; t < 17; ++t) {
            int col = t * 16 + lr;
            float bv = bias[col];
#pragma unroll
            for (int r = 0; r < 4; ++r) {
                int row = w * 16 + lk * 4 + r;
                float v = acc[t][r] + bv + bf2f(lds[row * 272 + col]);
                acc[t][r] = v;
                sum[r] += v;
                sq[r] += v * v;
            }
        }
#pragma unroll
        for (int mask = 1; mask <= 8; mask <<= 1)
#pragma unroll
            for (int r = 0; r < 4; ++r) {
                sum[r] += __shfl_xor(sum[r], mask);
                sq[r] += __shfl_xor(sq[r], mask);
            }
        float mu[4], inv[4];
#pragma unroll
        for (int r = 0; r < 4; ++r) {
            mu[r] = sum[r] * (1.0f / D_T);
            float var = sq[r] * (1.0f / D_T) - mu[r] * mu[r];
            inv[r] = 1.0f / sqrtf(var + 1e-5f);
        }
        __syncthreads();  // resid fully consumed; safe to overwrite with y
#pragma unroll
        for (int t = 0; t < 17; ++t) {
            int col = t * 16 + lr;
            float wv = lnw[col], bb = lnb[col];
#pragma unroll
            for (int r = 0; r < 4; ++r) {
                int row = w * 16 + lk * 4 + r;
                ushort val = f2bf((acc[t][r] - mu[r]) * inv[r] * wv + bb);
                X1out[(size_t)(m0 + row) * D_TP + col] = val;
                lds[row * YSTR + col] = val;
            }
        }
        // zero y pad cols 272..287
        for (int i = tid; i < 64 * 16; i += 256) {
            int row = i >> 4, q = i & 15;
            lds[row * YSTR + 272 + q] = 0;
        }
        __syncthreads();  // y visible to all waves
    }

    // ================= phase B: h1 = relu(y @ B2t + bias2) =================
    {
        const int wr = w >> 1, wc = w & 1;
        const int rb0 = w * 32 + (lane >> 2);
        const int cb0 = (((lane & 3) ^ ((rb0 >> 1) & 3)) << 3);
        const int rb1 = rb0 + 16;
        const int cb1 = (((lane & 3) ^ ((rb1 >> 1) & 3)) << 3);

        for (int chunk = 0; chunk < 8; ++chunk) {
            const ushort* gB0 = &B2t[(size_t)(chunk * 128 + rb0) * D_TP + cb0];
            const ushort* gB1 = &B2t[(size_t)(chunk * 128 + rb1) * D_TP + cb1];
            auto stageB = [&](int buf, int s) {
                const int k0 = s << 5;
                __builtin_amdgcn_global_load_lds(
                    (const __attribute__((address_space(1))) void*)(gB0 + k0),
                    (__attribute__((address_space(3))) void*)(&lds[RING + buf * 4096 + w * 1024]),
                    16, 0, 0);
                __builtin_amdgcn_global_load_lds(
                    (const __attribute__((address_space(1))) void*)(gB1 + k0),
                    (__attribute__((address_space(3))) void*)(&lds[RING + buf * 4096 + w * 1024 + 512]),
                    16, 0, 0);
            };

            f32x4 accb[2][4];
#pragma unroll
            for (int i = 0; i < 2; ++i)
#pragma unroll
                for (int j = 0; j < 4; ++j) accb[i][j] = (f32x4){0.f, 0.f, 0.f, 0.f};

            stageB(0, 0);
            stageB(1, 1);
            asm volatile("s_waitcnt vmcnt(2)" ::: "memory");
            __builtin_amdgcn_sched_barrier(0);
            __builtin_amdgcn_s_barrier();
            __builtin_amdgcn_sched_barrier(0);

            int cur = 0;
            for (int s = 0; s < 9; ++s) {
                int stg = cur + 2; if (stg >= 3) stg -= 3;
                if (s + 2 < 9) stageB(stg, s + 2);

                bf16x8 af2[2], bf2[4];
#pragma unroll
                for (int mt = 0; mt < 2; ++mt) {
                    int row = wr * 32 + mt * 16 + lr;
                    af2[mt] = *reinterpret_cast<const bf16x8*>(
                        &lds[row * YSTR + (s << 5) + lk * 8]);
                }
#pragma unroll
                for (int nt = 0; nt < 4; ++nt) {
                    int rowb = wc * 64 + nt * 16 + lr;
                    int ch = lk ^ ((rowb >> 1) & 3);
                    bf2[nt] = *reinterpret_cast<const bf16x8*>(
                        &lds[RING + cur * 4096 + rowb * 32 + ch * 8]);
                }
                __builtin_amdgcn_s_setprio(1);
#pragma unroll
                for (int mt = 0; mt < 2; ++mt)
#pragma unroll
                    for (int nt = 0; nt < 4; ++nt)
                        accb[mt][nt] = __builtin_amdgcn_mfma_f32_16x16x32_bf16(
                            af2[mt], bf2[nt], accb[mt][nt], 0, 0, 0);
                __builtin_amdgcn_s_setprio(0);

                if (s + 1 < 9) {
                    if (s + 2 < 9)
                        asm volatile("s_waitcnt vmcnt(2)" ::: "memory");
                    else
                        asm volatile("s_waitcnt vmcnt(0)" ::: "memory");
                    __builtin_amdgcn_sched_barrier(0);
                    __builtin_amdgcn_s_barrier();
                    __builtin_amdgcn_sched_barrier(0);
                }
                cur = (cur == 2) ? 0 : cur + 1;
            }

            // epilogue: h1 chunk write with relu
#pragma unroll
            for (int nt = 0; nt < 4; ++nt) {
                int col = chunk * 128 + wc * 64 + nt * 16 + lr;
                float bv = bias2[col];
#pragma unroll
                for (int mt = 0; mt < 2; ++mt)
#pragma unroll
                    for (int r = 0; r < 4; ++r) {
                        int row = m0 + wr * 32 + mt * 16 + lk * 4 + r;
                        H1out[(size_t)row * 1024 + col] =
                            f2bf(fmaxf(accb[mt][nt][r] + bv, 0.f));
                    }
            }
        }
    }
}

// ---------------------------------------------------------------------------
// Fused GEMM(+bias) + residual + LayerNorm, N=272 (FFN2 path, K=1024).
// ---------------------------------------------------------------------------
__global__ __launch_bounds__(256) void gemm_ln(const ushort* __restrict__ A,
                                               const ushort* __restrict__ Bt,
                                               const float* __restrict__ bias,
                                               const ushort* __restrict__ resid,
                                               const float* __restrict__ lnw,
                                               const float* __restrict__ lnb,
                                               ushort* __restrict__ Out,
                                               int K, int Kstride) {
    __shared__ ushort lds[32256];  // As: 3x2048 @0 ; Bs: 3x8704 @6144
    const int tid = threadIdx.x;
    const int m0 = blockIdx.x * 64;
    const int w = tid >> 6, lane = tid & 63;
    const int lr = lane & 15, lk = lane >> 4;
    const int ns = K >> 5;

    const int ra = w * 16 + (lane >> 2);
    const int ca = (((lane & 3) ^ ((ra >> 1) & 3)) << 3);
    const ushort* gA = &A[(size_t)(m0 + ra) * Kstride + ca];

    f32x4 acc[17];
#pragma unroll
    for (int t = 0; t < 17; ++t) acc[t] = (f32x4){0.f, 0.f, 0.f, 0.f};

    auto stage = [&](int buf, int s) {
        const int k0 = s << 5;
        __builtin_amdgcn_global_load_lds(
            (const __attribute__((address_space(1))) void*)(gA + k0),
            (__attribute__((address_space(3))) void*)(&lds[buf * 2048 + w * 512]),
            16, 0, 0);
        for (int c = w; c < 17; c += 4) {
            int row16 = c * 16 + (lane >> 2);
            int p8 = (((lane & 3) ^ ((row16 >> 1) & 3)) << 3);
            const ushort* src = &Bt[(size_t)row16 * Kstride + k0 + p8];
            __builtin_amdgcn_global_load_lds(
                (const __attribute__((address_space(1))) void*)src,
                (__attribute__((address_space(3))) void*)(&lds[6144 + buf * 8704 + c * 512]),
                16, 0, 0);
        }
    };

    stage(0, 0);
    stage(1, 1);
    if (w == 0)
        asm volatile("s_waitcnt vmcnt(6)" ::: "memory");
    else
        asm volatile("s_waitcnt vmcnt(5)" ::: "memory");
    __builtin_amdgcn_sched_barrier(0);
    __builtin_amdgcn_s_barrier();
    __builtin_amdgcn_sched_barrier(0);

    int cur = 0;
    for (int s = 0; s < ns; ++s) {
        int stg = cur + 2; if (stg >= 3) stg -= 3;
        if (s + 2 < ns) stage(stg, s + 2);

        bf16x8 af;
        {
            int row = w * 16 + lr;
            int ch = lk ^ ((row >> 1) & 3);
            af = *reinterpret_cast<const bf16x8*>(&lds[cur * 2048 + row * 32 + ch * 8]);
        }
        __builtin_amdgcn_s_setprio(1);
#pragma unroll
        for (int t = 0; t < 17; ++t) {
            int row = t * 16 + lr;
            int ch = lk ^ ((row >> 1) & 3);
            bf16x8 bf = *reinterpret_cast<const bf16x8*>(
                &lds[6144 + cur * 8704 + row * 32 + ch * 8]);
            acc[t] = __builtin_amdgcn_mfma_f32_16x16x32_bf16(af, bf, acc[t], 0, 0, 0);
        }
        __builtin_amdgcn_s_setprio(0);

        if (s + 1 < ns) {
            if (s + 2 < ns) {
                if (w == 0)
                    asm volatile("s_waitcnt vmcnt(6)" ::: "memory");
                else
                    asm volatile("s_waitcnt vmcnt(5)" ::: "memory");
            } else {
                asm volatile("s_waitcnt vmcnt(0)" ::: "memory");
            }
            __builtin_amdgcn_sched_barrier(0);
            __builtin_amdgcn_s_barrier();
            __builtin_amdgcn_sched_barrier(0);
        }
        cur = (cur == 2) ? 0 : cur + 1;
    }

    __syncthreads();
    for (int i = tid; i < 64 * 34; i += 256) {
        int row = i / 34, c8 = i - row * 34;
        *reinterpret_cast<uint4*>(&lds[row * 272 + c8 * 8]) =
            *reinterpret_cast<const uint4*>(&resid[(size_t)(m0 + row) * D_TP + c8 * 8]);
    }
    __syncthreads();

    float sum[4] = {0.f, 0.f, 0.f, 0.f}, sq[4] = {0.f, 0.f, 0.f, 0.f};
#pragma unroll
    for (int t = 0; t < 17; ++t) {
        int col = t * 16 + lr;
        float bv = bias[col];
#pragma unroll
        for (int r = 0; r < 4; ++r) {
            int row = w * 16 + lk * 4 + r;
            float v = acc[t][r] + bv + bf2f(lds[row * 272 + col]);
            acc[t][r] = v;
            sum[r] += v;
            sq[r] += v * v;
        }
    }
#pragma unroll
    for (int mask = 1; mask <= 8; mask <<= 1)
#pragma unroll
        for (int r = 0; r < 4; ++r) {
            sum[r] += __shfl_xor(sum[r], mask);
            sq[r] += __shfl_xor(sq[r], mask);
        }
    float mu[4], inv[4];
#pragma unroll
    for (int r = 0; r < 4; ++r) {
        mu[r] = sum[r] * (1.0f / D_T);
        float var = sq[r] * (1.0f / D_T) - mu[r] * mu[r];
        inv[r] = 1.0f / sqrtf(var + 1e-5f);
    }
#pragma unroll
    for (int t = 0; t < 17; ++t) {
        int col = t * 16 + lr;
        float wv = lnw[col], bb = lnb[col];
#pragma unroll
        for (int r = 0; r < 4; ++r) {
            int row = m0 + w * 16 + lk * 4 + r;
            Out[(size_t)row * D_TP + col] = f2bf((acc[t][r] - mu[r]) * inv[r] * wv + bb);
        }
    }
}

// ---------------------------------------------------------------------------
// seq[t,b,c] (stride 288): c<256 -> relu(bv2 + sum_ks p2p) expand; c<272 PE;
// else 0. (prop2 split-K reduce fused in.)
// ---------------------------------------------------------------------------
__global__ void seq_kernel(const float* __restrict__ p2p, const float* __restrict__ bv2,
                           const float* __restrict__ times, ushort* __restrict__ seq) {
    int idx = blockIdx.x * blockDim.x + threadIdx.x;
    if (idx >= T_DIM * B_DIM * D_TP) return;
    int c = idx % D_TP;
    int tb = idx / D_TP;
    float v;
    if (c < 256) {
        int b = tb % B_DIM;
        int g = ((tb / B_DIM) << 2) + (c & 3);
        float s = bv2[g];
#pragma unroll
        for (int ks = 0; ks < 4; ++ks)
            s += p2p[(size_t)(ks * B_DIM + b) * F_INF + g];
        v = fmaxf(s, 0.f);
    } else if (c < 272) {
        int s = c - 256;
        int sc = (s < 8) ? s : s - 8;
        float arg = times[tb] * exp2f(-8.0f * (float)sc * (1.0f / 7.0f));
        v = (s < 8) ? sinf(arg) : cosf(arg);
    } else {
        v = 0.f;
    }
    seq[idx] = f2bf(v);
}

// ---------------------------------------------------------------------------
// MFMA flash attention (validated round 6; attno stride 288).
// ---------------------------------------------------------------------------
__global__ __launch_bounds__(256) void attn_mfma(const ushort* __restrict__ qkv,
                                                 const int* __restrict__ lengths,
                                                 ushort* __restrict__ attno) {
    const int b = blockIdx.x >> 3;
    const int h = blockIdx.x & 7;
    const int tid = threadIdx.x;
    const int w = tid >> 6, lane = tid & 63;
    const int lr = lane & 15, lk = lane >> 4;
    __shared__ ushort Ks[2][64 * 40];
    __shared__ ushort Vt[2][48 * 72];
    __shared__ ushort Ps[4][64 * 72];
    const int len = lengths[b];
    const float scale = 0.1714985851f;  // 1/sqrt(34)
    const bf16x8 zv = {0, 0, 0, 0, 0, 0, 0, 0};

    for (int i = tid; i < 2 * 8 * 72; i += 256) {
        int bb = i / 576;
        Vt[bb][40 * 72 + (i - bb * 576)] = 0;
    }

    const int srow0 = tid / 5, sch0 = tid - srow0 * 5;
    const int srow1 = (tid + 256) / 5, sch1 = (tid + 256) - srow1 * 5;
    const int sjp0 = (srow0 & 15) * 4 + (srow0 >> 4);
    const int sjp1 = (srow1 & 15) * 4 + (srow1 >> 4);
    const bool has1 = (tid < 64);
    bf16x8 kreg0, kreg1, vreg0, vreg1;

    auto LOADS = [&](int c) {
        const ushort* b0 = &qkv[(size_t)((c * 64 + srow0) * 32 + b) * 960 + h * 40];
        kreg0 = *reinterpret_cast<const bf16x8*>(b0 + 320 + sch0 * 8);
        vreg0 = *reinterpret_cast<const bf16x8*>(b0 + 640 + sch0 * 8);
        if (has1) {
            const ushort* b1 = &qkv[(size_t)((c * 64 + srow1) * 32 + b) * 960 + h * 40];
            kreg1 = *reinterpret_cast<const bf16x8*>(b1 + 320 + sch1 * 8);
            vreg1 = *reinterpret_cast<const bf16x8*>(b1 + 640 + sch1 * 8);
        }
    };
    auto WRITES = [&](int buf) {
        *reinterpret_cast<bf16x8*>(&Ks[buf][srow0 * 40 + sch0 * 8]) = kreg0;
#pragma unroll
        for (int e = 0; e < 8; ++e) Vt[buf][(sch0 * 8 + e) * 72 + sjp0] = (ushort)vreg0[e];
        if (has1) {
            *reinterpret_cast<bf16x8*>(&Ks[buf][srow1 * 40 + sch1 * 8]) = kreg1;
#pragma unroll
            for (int e = 0; e < 8; ++e) Vt[buf][(sch1 * 8 + e) * 72 + sjp1] = (ushort)vreg1[e];
        }
    };

    bf16x8 qf0[4], qf1[4];
#pragma unroll
    for (int it = 0; it < 4; ++it) {
        int t = w * 64 + it * 16 + lr;
        const ushort* qrow = &qkv[(size_t)(t * 32 + b) * 960 + h * 40];
        qf0[it] = *reinterpret_cast<const bf16x8*>(qrow + lk * 8);
        qf1[it] = (lk == 0) ? *reinterpret_cast<const bf16x8*>(qrow + 32) : zv;
    }

    f32x4 oacc[4][3];
#pragma unroll
    for (int it = 0; it < 4; ++it)
#pragma unroll
        for (int dt = 0; dt < 3; ++dt) oacc[it][dt] = (f32x4){0.f, 0.f, 0.f, 0.f};
    float m[4][4], l[4][4];
#pragma unroll
    for (int it = 0; it < 4; ++it)
#pragma unroll
        for (int r = 0; r < 4; ++r) { m[it][r] = -1e30f; l[it][r] = 0.f; }

    const int nchunks = (len + 63) >> 6;
    LOADS(0);
    WRITES(0);
    __syncthreads();

    int cur = 0;
    for (int c = 0; c < nchunks; ++c) {
        const bool pre = (c + 1 < nchunks);
        if (pre) LOADS(c + 1);

        bf16x8 kf0[4], kf1[4];
#pragma unroll
        for (int jt = 0; jt < 4; ++jt) {
            int j = jt * 16 + lr;
            kf0[jt] = *reinterpret_cast<const bf16x8*>(&Ks[cur][j * 40 + lk * 8]);
            kf1[jt] = (lk == 0) ? *reinterpret_cast<const bf16x8*>(&Ks[cur][j * 40 + 32]) : zv;
        }

        const bool tail = (c * 64 + 64 > len);
#pragma unroll
        for (int it = 0; it < 4; ++it) {
            f32x4 sacc[4];
#pragma unroll
            for (int jt = 0; jt < 4; ++jt) sacc[jt] = (f32x4){0.f, 0.f, 0.f, 0.f};
            __builtin_amdgcn_s_setprio(1);
#pragma unroll
            for (int jt = 0; jt < 4; ++jt) {
                sacc[jt] = __builtin_amdgcn_mfma_f32_16x16x32_bf16(qf0[it], kf0[jt],
                                                                   sacc[jt], 0, 0, 0);
                sacc[jt] = __builtin_amdgcn_mfma_f32_16x16x32_bf16(qf1[it], kf1[jt],
                                                                   sacc[jt], 0, 0, 0);
            }
            __builtin_amdgcn_s_setprio(0);
            float cm[4] = {-1e30f, -1e30f, -1e30f, -1e30f};
#pragma unroll
            for (int jt = 0; jt < 4; ++jt) {
                bool dead = tail && (c * 64 + jt * 16 + lr >= len);
#pragma unroll
                for (int r = 0; r < 4; ++r) {
                    float sv = dead ? -1e30f : sacc[jt][r];
                    sacc[jt][r] = sv;
                    cm[r] = fmaxf(cm[r], sv);
                }
            }
#pragma unroll
            for (int mask = 1; mask <= 8; mask <<= 1)
#pragma unroll
                for (int r = 0; r < 4; ++r) cm[r] = fmaxf(cm[r], __shfl_xor(cm[r], mask));
#pragma unroll
            for (int r = 0; r < 4; ++r) {
                float mn = fmaxf(m[it][r], cm[r]);
                float corr = __expf((m[it][r] - mn) * scale);
                m[it][r] = mn;
                l[it][r] *= corr;
#pragma unroll
                for (int dt = 0; dt < 3; ++dt) oacc[it][dt][r] *= corr;
            }
            float ls[4] = {0.f, 0.f, 0.f, 0.f};
#pragma unroll
            for (int jt = 0; jt < 4; ++jt)
#pragma unroll
                for (int r = 0; r < 4; ++r) {
                    float e = __expf((sacc[jt][r] - m[it][r]) * scale);
                    sacc[jt][r] = e;
                    ls[r] += e;
                }
#pragma unroll
            for (int mask = 1; mask <= 8; mask <<= 1)
#pragma unroll
                for (int r = 0; r < 4; ++r) ls[r] += __shfl_xor(ls[r], mask);
#pragma unroll
            for (int r = 0; r < 4; ++r) l[it][r] += ls[r];
#pragma unroll
            for (int r = 0; r < 4; ++r) {
                int i = it * 16 + lk * 4 + r;
                uint u0 = (uint)f2bf(sacc[0][r]) | ((uint)f2bf(sacc[1][r]) << 16);
                uint u1 = (uint)f2bf(sacc[2][r]) | ((uint)f2bf(sacc[3][r]) << 16);
                uint2 pk = make_uint2(u0, u1);
                *reinterpret_cast<uint2*>(&Ps[w][i * 72 + lr * 4]) = pk;
            }
        }

        bf16x8 vf[3][2], pf[4][2];
#pragma unroll
        for (int dt = 0; dt < 3; ++dt)
#pragma unroll
            for (int ks = 0; ks < 2; ++ks)
                vf[dt][ks] = *reinterpret_cast<const bf16x8*>(
                    &Vt[cur][(dt * 16 + lr) * 72 + ks * 32 + lk * 8]);
#pragma unroll
        for (int it = 0; it < 4; ++it)
#pragma unroll
            for (int ks = 0; ks < 2; ++ks)
                pf[it][ks] = *reinterpret_cast<const bf16x8*>(
                    &Ps[w][(it * 16 + lr) * 72 + ks * 32 + lk * 8]);
        __builtin_amdgcn_s_setprio(1);
#pragma unroll
        for (int it = 0; it < 4; ++it)
#pragma unroll
            for (int dt = 0; dt < 3; ++dt)
#pragma unroll
                for (int ks = 0; ks < 2; ++ks)
                    oacc[it][dt] = __builtin_amdgcn_mfma_f32_16x16x32_bf16(
                        pf[it][ks], vf[dt][ks], oacc[it][dt], 0, 0, 0);
        __builtin_amdgcn_s_setprio(0);

        if (pre) WRITES(cur ^ 1);
        __syncthreads();
        cur ^= 1;
    }

#pragma unroll
    for (int it = 0; it < 4; ++it)
#pragma unroll
        for (int r = 0; r < 4; ++r) {
            float inv = 1.0f / l[it][r];
            int t = w * 64 + it * 16 + lk * 4 + r;
            ushort* orow = &attno[(size_t)(t * 32 + b) * D_TP + h * 34];
#pragma unroll
            for (int dt = 0; dt < 3; ++dt) {
                int d = dt * 16 + lr;
                if (d < 34) orow[d] = f2bf(oacc[it][dt][r] * inv);
            }
        }
}

// ---------------------------------------------------------------------------
// pool stage 1: partial[chunk][b][272] over 32 t-rows (seq stride 288).
// ---------------------------------------------------------------------------
__global__ __launch_bounds__(256) void pool_partial(const ushort* __restrict__ seq,
                                                    const int* __restrict__ lengths,
                                                    float* __restrict__ partial) {
    const int chunk = blockIdx.x;
    const int b = blockIdx.y;
    const int tid = threadIdx.x;
    if (tid >= 136) return;
    const int len = lengths[b];
    float s0 = 0.f, s1 = 0.f;
    int t0 = chunk * 32;
    int tmax = len - t0;
    if (tmax > 32) tmax = 32;
#pragma unroll 4
    for (int r = 0; r < tmax; ++r) {
        uint u = *reinterpret_cast<const uint*>(
            &seq[(size_t)((t0 + r) * B_DIM + b) * D_TP + tid * 2]);
        s0 += __uint_as_float(u << 16);
        s1 += __uint_as_float(u & 0xffff0000u);
    }
    float* p = &partial[(size_t)(chunk * B_DIM + b) * D_T + tid * 2];
    p[0] = s0;
    p[1] = s1;
}

// ---------------------------------------------------------------------------
// head: agg = (sum partials)/(len+1); hid = relu(agg@w1+b1);
// logits = hid@w2+b2; softmax. One block per b.
// ---------------------------------------------------------------------------
__global__ __launch_bounds__(256) void head_kernel(const float* __restrict__ partial,
                                                   const int* __restrict__ lengths,
                                                   const float* __restrict__ w1,
                                                   const float* __restrict__ b1,
                                                   const float* __restrict__ w2,
                                                   const float* __restrict__ b2,
                                                   float* __restrict__ out) {
    const int b = blockIdx.x;
    const int tid = threadIdx.x;
    const int len = lengths[b];
    __shared__ float agg_s[D_T];
    __shared__ float hid[D_T];
    float inv = 1.0f / (float)(len + 1);
    for (int c = tid; c < D_T; c += 256) {
        float s = 0.f;
#pragma unroll
        for (int ch = 0; ch < 8; ++ch)
            s += partial[(size_t)(ch * B_DIM + b) * D_T + c];
        agg_s[c] = s * inv;
    }
    __syncthreads();
    for (int j = tid; j < D_T; j += 256) {
        float acc = b1[j];
        for (int k = 0; k < D_T; ++k) acc += agg_s[k] * w1[k * D_T + j];
        hid[j] = fmaxf(acc, 0.f);
    }
    __syncthreads();
    if (tid < 64) {
        float l0 = 0.f, l1 = 0.f;
        for (int k = tid; k < D_T; k += 64) {
            float hv = hid[k];
            l0 += hv * w2[k * 2 + 0];
            l1 += hv * w2[k * 2 + 1];
        }
#pragma unroll
        for (int off = 32; off; off >>= 1) {
            l0 += __shfl_down(l0, off);
            l1 += __shfl_down(l1, off);
        }
        if (tid == 0) {
            l0 += b2[0];
            l1 += b2[1];
            float mx = fmaxf(l0, l1);
            float e0 = expf(l0 - mx), e1 = expf(l1 - mx);
            float nrm = 1.0f / (e0 + e1);
            out[b * 2 + 0] = e0 * nrm;
            out[b * 2 + 1] = e1 * nrm;
        }
    }
}

// ---------------------------------------------------------------------------
extern "C" void kernel_launch(void* const* d_in, const int* in_sizes, int n_in,
                              void* d_out, int out_size, void* d_ws, size_t ws_size,
                              hipStream_t stream) {
    const float* x      = (const float*)d_in[0];
    const float* times  = (const float*)d_in[1];
    const int*   lens   = (const int*)d_in[2];
    const float* R_u    = (const float*)d_in[3];
    const float* Wv1    = (const float*)d_in[4];
    const float* bv1    = (const float*)d_in[5];
    const float* Wv2    = (const float*)d_in[6];
    const float* bv2    = (const float*)d_in[7];
    const float* qkv_w  = (const float*)d_in[8];
    const float* qkv_b  = (const float*)d_in[9];
    const float* out_w  = (const float*)d_in[10];
    const float* out_b  = (const float*)d_in[11];
    const float* ln1_w  = (const float*)d_in[12];
    const float* ln1_b  = (const float*)d_in[13];
    const float* ln2_w  = (const float*)d_in[14];
    const float* ln2_b  = (const float*)d_in[15];
    const float* ffn_w1 = (const float*)d_in[16];
    const float* ffn_b1 = (const float*)d_in[17];
    const float* ffn_w2 = (const float*)d_in[18];
    const float* ffn_b2 = (const float*)d_in[19];
    const float* mlp_w1 = (const float*)d_in[20];
    const float* mlp_b1 = (const float*)d_in[21];
    const float* mlp_w2 = (const float*)d_in[22];
    const float* mlp_b2 = (const float*)d_in[23];
    float* outp = (float*)d_out;

    char* base = (char*)d_ws;
    size_t used = 0;
    auto alloc = [&](size_t bytes) -> char* {
        char* p = base + used;
        used += (bytes + 255) & ~(size_t)255;
        return p;
    };
    const int TB = T_DIM * B_DIM;  // 8192

    ushort* xn    = (ushort*)alloc((size_t)2048 * 1024 * 2);
    ushort* s1    = (ushort*)alloc((size_t)32 * 1024 * 2);
    float*  p2p   = (float*) alloc((size_t)4 * 32 * 1024 * 4);
    ushort* seq   = (ushort*)alloc((size_t)TB * D_TP * 2);
    ushort* qkvb  = (ushort*)alloc((size_t)TB * 960 * 2);
    ushort* attno = (ushort*)alloc((size_t)TB * D_TP * 2);
    ushort* x1    = (ushort*)alloc((size_t)TB * D_TP * 2);
    ushort* h1    = (ushort*)alloc((size_t)TB * DFF_DIM * 2);
    float*  ppart = (float*) alloc((size_t)8 * B_DIM * D_T * 4);
    ushort* wv1t  = (ushort*)alloc((size_t)1024 * 1024 * 2);
    ushort* wv2t  = (ushort*)alloc((size_t)1024 * 1024 * 2);
    ushort* qkvwt[2]; ushort* outwt[2]; ushort* f1wt[2]; ushort* f2wt[2];
    for (int l = 0; l < 2; ++l) {
        qkvwt[l] = (ushort*)alloc((size_t)816 * D_TP * 2);
        outwt[l] = (ushort*)alloc((size_t)272 * D_TP * 2);
        f1wt[l]  = (ushort*)alloc((size_t)1024 * D_TP * 2);
        f2wt[l]  = (ushort*)alloc((size_t)272 * 1024 * 2);
    }
    if (used > ws_size) return;

    // ---- merged wconv + init (1 dispatch) ----
    {
        WT segs;
        const float* srcs[10] = {Wv1, Wv2,
                                 qkv_w, out_w, ffn_w1, ffn_w2,
                                 qkv_w + (size_t)272 * 816, out_w + (size_t)272 * 272,
                                 ffn_w1 + (size_t)272 * 1024, ffn_w2 + (size_t)1024 * 272};
        ushort* dsts[10] = {wv1t, wv2t, qkvwt[0], outwt[0], f1wt[0], f2wt[0],
                            qkvwt[1], outwt[1], f1wt[1], f2wt[1]};
        int Ksz[10] = {1024, 1024, 272, 272, 272, 1024, 272, 272, 272, 1024};
        int Nsz[10] = {1024, 1024, 816, 272, 1024, 272, 816, 272, 1024, 272};
        int Kpd[10] = {1024, 1024, D_TP, D_TP, D_TP, 1024, D_TP, D_TP, D_TP, 1024};
        int acc = 0;
        for (int i = 0; i < 10; ++i) {
            segs.tstart[i] = acc;
            segs.src[i] = srcs[i];
            segs.dst[i] = dsts[i];
            segs.N[i] = Nsz[i];
            segs.Kp[i] = Kpd[i];
            segs.ntn[i] = Nsz[i] / 16;
            acc += (Ksz[i] / 16) * (Nsz[i] / 16);
        }
        segs.tstart[10] = acc;

        PadPtrs pp;
        pp.wt[0] = (uint*)qkvwt[0]; pp.nrows[0] = 816;
        pp.wt[1] = (uint*)qkvwt[1]; pp.nrows[1] = 816;
        pp.wt[2] = (uint*)outwt[0]; pp.nrows[2] = 272;
        pp.wt[3] = (uint*)outwt[1]; pp.nrows[3] = 272;
        pp.wt[4] = (uint*)f1wt[0];  pp.nrows[4] = 1024;
        pp.wt[5] = (uint*)f1wt[1];  pp.nrows[5] = 1024;
        int ninit = B_DIM * N_DIM * F_INF + TB * 8 + TB * 72 +
                    (816 + 816 + 272 + 272 + 1024 + 1024) * 8;
        int nblk = acc + (ninit + 255) / 256;
        wconv_init<<<nblk, 256, 0, stream>>>(segs, acc, x, R_u, xn, (uint*)qkvb,
                                             (uint*)x1, (uint*)attno, pp);
    }

    // prop1 fused: [2048,1024]@[1024,1024] + relu + row-mean -> s1 [32][1024]
    gemm_mfma<1, 4><<<dim3(8, 32), 256, 0, stream>>>(xn, wv1t, bv1, s1,
                                                     2048, 1024, 1024, 1024);
    // prop2 split-K x4 -> p2p partials
    gemm_mfma<0, 3><<<dim3(8, 4), 256, 0, stream>>>(s1, wv2t, nullptr, p2p,
                                                    32, 1024, 256, 1024);
    // seq build (p2 reduce + relu + PE fused)
    {
        int n = TB * D_TP;
        seq_kernel<<<(n + 255) / 256, 256, 0, stream>>>(p2p, bv2, times, seq);
    }

    for (int l = 0; l < 2; ++l) {
        const float* qb  = qkv_b + (size_t)l * 816;
        const float* ob  = out_b + (size_t)l * D_T;
        const float* l1w = ln1_w + (size_t)l * D_T;
        const float* l1b = ln1_b + (size_t)l * D_T;
        const float* l2w = ln2_w + (size_t)l * D_T;
        const float* l2b = ln2_b + (size_t)l * D_T;
        const float* f1b = ffn_b1 + (size_t)l * DFF_DIM;
        const float* f2b = ffn_b2 + (size_t)l * D_T;

        // QKV: [8192,288]@[288,816] -> bf16 head-padded
        gemm_mfma<0, 2><<<dim3(7, 128), 256, 0, stream>>>(seq, qkvwt[l], qb, qkvb,
                                                          TB, 816, D_TP, D_TP);
        attn_mfma<<<B_DIM * H_DIM, 256, 0, stream>>>(qkvb, lens, attno);
        // out-proj + resid(seq) + LN1 -> x1, then FFN1 -> h1 (fused)
        gemm_ln_ffn<<<128, 256, 0, stream>>>(attno, outwt[l], ob, seq, l1w, l1b, x1,
                                             f1wt[l], f1b, h1);
        // FFN2 + resid(x1) + LN2 -> seq
        gemm_ln<<<128, 256, 0, stream>>>(h1, f2wt[l], f2b, x1, l2w, l2b, seq,
                                         1024, 1024);
    }

    pool_partial<<<dim3(8, B_DIM), 256, 0, stream>>>(seq, lens, ppart);
    head_kernel<<<B_DIM, 256, 0, stream>>>(ppart, lens, mlp_w1, mlp_b1,
                                           mlp_w2, mlp_b2, outp);
}

// Round 13
// 286.553 us; speedup vs baseline: 1.0266x; 1.0266x over previous
//
#include <hip/hip_runtime.h>
#include <math.h>

#define T_DIM 256
#define B_DIM 32
#define N_DIM 64
#define F_INF 1024
#define D_T 272
#define D_TP 288   // K-padded row stride for 272-wide activations
#define H_DIM 8
#define DH_DIM 34
#define DFF_DIM 1024

typedef unsigned int uint;
typedef short bf16x8 __attribute__((ext_vector_type(8)));
typedef float f32x4 __attribute__((ext_vector_type(4)));

__device__ __forceinline__ ushort f2bf(float f) {
    uint u = __float_as_uint(f);
    uint r = (u + 0x7fffu + ((u >> 16) & 1u)) >> 16;
    return (ushort)r;
}
__device__ __forceinline__ float bf2f(ushort u) {
    return __uint_as_float(((uint)u) << 16);
}

// ---------------------------------------------------------------------------
// xn[b,n,t*4+d] = relu(x[t,b,n] * R_u[n*4+d])  -> bf16
// ---------------------------------------------------------------------------
__global__ void xn_kernel(const float* __restrict__ x, const float* __restrict__ Ru,
                          ushort* __restrict__ xn) {
    int idx = blockIdx.x * blockDim.x + threadIdx.x;
    if (idx >= B_DIM * N_DIM * F_INF) return;
    int f = idx & 1023;
    int bn = idx >> 10;
    int n = bn & 63;
    int b = bn >> 6;
    int t = f >> 2;
    int d = f & 3;
    float v = x[(t * B_DIM + b) * N_DIM + n] * Ru[(n << 2) + d];
    xn[idx] = f2bf(fmaxf(v, 0.0f));
}

// ---------------------------------------------------------------------------
// tiled weight convert+transpose: f32 [K,N] -> bf16 [N,Kp].
// ---------------------------------------------------------------------------
struct WT {
    int tstart[11];
    const float* src[10];
    ushort* dst[10];
    int K[10];
    int N[10];
    int Kp[10];
    int ntn[10];  // N/16
};
__global__ __launch_bounds__(256) void wconv_tiled(WT s) {
    int tile = blockIdx.x;
    int seg = 0;
    while (seg < 9 && tile >= s.tstart[seg + 1]) ++seg;
    int ti = tile - s.tstart[seg];
    int ntn = s.ntn[seg];
    int tk = ti / ntn, tn = ti - tk * ntn;
    int N = s.N[seg], Kp = s.Kp[seg];
    __shared__ float t[16][17];
    int ty = threadIdx.x >> 4, tx = threadIdx.x & 15;
    t[ty][tx] = s.src[seg][(size_t)(tk * 16 + ty) * N + tn * 16 + tx];
    __syncthreads();
    s.dst[seg][(size_t)(tn * 16 + ty) * Kp + tk * 16 + tx] = f2bf(t[tx][ty]);
}

// ---------------------------------------------------------------------------
// merged init: xn elementwise + all one-time pad zeroing.
// ---------------------------------------------------------------------------
struct PadPtrs {
    uint* wt[6];
    int nrows[6];
};
__global__ void init_kernel(const float* __restrict__ x, const float* __restrict__ Ru,
                            ushort* __restrict__ xn, uint* __restrict__ qkvb,
                            uint* __restrict__ x1, uint* __restrict__ attno, PadPtrs p) {
    const int TB = T_DIM * B_DIM;
    const int NXN = B_DIM * N_DIM * F_INF;
    int idx = blockIdx.x * blockDim.x + threadIdx.x;
    if (idx < NXN) {
        int f = idx & 1023;
        int bn = idx >> 10;
        int n = bn & 63;
        int b = bn >> 6;
        int t = f >> 2;
        int d = f & 3;
        float v = x[(t * B_DIM + b) * N_DIM + n] * Ru[(n << 2) + d];
        xn[idx] = f2bf(fmaxf(v, 0.0f));
        return;
    }
    idx -= NXN;
    if (idx < TB * 8) {
        int row = idx >> 3, q = idx & 7;
        x1[(size_t)row * 144 + 136 + q] = 0;
        attno[(size_t)row * 144 + 136 + q] = 0;
        return;
    }
    idx -= TB * 8;
    if (idx < TB * 72) {
        int row = idx / 72;
        int r = idx - row * 72;
        int g = r / 3, q = r - g * 3;
        qkvb[(size_t)row * 480 + g * 20 + 17 + q] = 0;
        return;
    }
    idx -= TB * 72;
#pragma unroll
    for (int sgi = 0; sgi < 6; ++sgi) {
        int cnt = p.nrows[sgi] * 8;
        if (idx < cnt) {
            int row = idx >> 3, q = idx & 7;
            p.wt[sgi][(size_t)row * 144 + 136 + q] = 0;
            return;
        }
        idx -= cnt;
    }
}

// ---------------------------------------------------------------------------
// MFMA bf16 GEMM, 3-deep ring, counted vmcnt (validated round 8).
// BM=64, BN=128, BK=32; 256 thr = 4 waves (2x2), wave tile 32x64.
// OUT_MODE: 0 f32 flat, 1 bf16 flat, 2 bf16 head-padded QKV,
//           3 f32 split-K partial, 4 prop1-fused row-reduce -> s1 bf16.
// ---------------------------------------------------------------------------
template <int ACT, int OUT_MODE>
__global__ __launch_bounds__(256) void gemm_mfma(const ushort* __restrict__ A,
                                                 const ushort* __restrict__ Bt,
                                                 const float* __restrict__ bias,
                                                 void* __restrict__ Cout,
                                                 int M, int N, int K, int Kstride) {
    __shared__ ushort As[3][64 * 32];
    __shared__ ushort Bs[3][128 * 32];
    const int tid = threadIdx.x;
    const int m0 = (OUT_MODE == 3) ? 0 : blockIdx.y * 64;
    const int n0 = blockIdx.x * 128;
    if (OUT_MODE == 3) {
        A += (size_t)blockIdx.y * K;
        Bt += (size_t)blockIdx.y * K;
    }
    const int w = tid >> 6, lane = tid & 63;
    const int wr = w >> 1, wc = w & 1;
    const int lr = lane & 15, lk = lane >> 4;

    const int ns = K >> 5;

    const int ra = w * 16 + (lane >> 2);
    const int ca = (((lane & 3) ^ ((ra >> 1) & 3)) << 3);
    int gma = m0 + ra; if (gma > M - 1) gma = M - 1;
    const ushort* gA = &A[(size_t)gma * Kstride + ca];
    const int rb0 = w * 32 + (lane >> 2);
    const int cb0 = (((lane & 3) ^ ((rb0 >> 1) & 3)) << 3);
    const int rb1 = rb0 + 16;
    const int cb1 = (((lane & 3) ^ ((rb1 >> 1) & 3)) << 3);
    int gnb0 = n0 + rb0; if (gnb0 > N - 1) gnb0 = N - 1;
    int gnb1 = n0 + rb1; if (gnb1 > N - 1) gnb1 = N - 1;
    const ushort* gB0 = &Bt[(size_t)gnb0 * Kstride + cb0];
    const ushort* gB1 = &Bt[(size_t)gnb1 * Kstride + cb1];

    f32x4 acc[2][4];
#pragma unroll
    for (int i = 0; i < 2; ++i)
#pragma unroll
        for (int j = 0; j < 4; ++j) acc[i][j] = (f32x4){0.f, 0.f, 0.f, 0.f};

    auto stage = [&](int buf, int s) {
        const int k0 = s << 5;
        __builtin_amdgcn_global_load_lds(
            (const __attribute__((address_space(1))) void*)(gA + k0),
            (__attribute__((address_space(3))) void*)(&As[buf][w * 512]), 16, 0, 0);
        __builtin_amdgcn_global_load_lds(
            (const __attribute__((address_space(1))) void*)(gB0 + k0),
            (__attribute__((address_space(3))) void*)(&Bs[buf][w * 1024]), 16, 0, 0);
        __builtin_amdgcn_global_load_lds(
            (const __attribute__((address_space(1))) void*)(gB1 + k0),
            (__attribute__((address_space(3))) void*)(&Bs[buf][w * 1024 + 512]), 16, 0, 0);
    };

    stage(0, 0);
    stage(1, 1);
    asm volatile("s_waitcnt vmcnt(3)" ::: "memory");
    __builtin_amdgcn_sched_barrier(0);
    __builtin_amdgcn_s_barrier();
    __builtin_amdgcn_sched_barrier(0);

    int cur = 0;
    for (int s = 0; s < ns; ++s) {
        int stg = cur + 2; if (stg >= 3) stg -= 3;
        if (s + 2 < ns) stage(stg, s + 2);

        bf16x8 af[2], bf[4];
#pragma unroll
        for (int mt = 0; mt < 2; ++mt) {
            int row = wr * 32 + mt * 16 + lr;
            int ch = lk ^ ((row >> 1) & 3);
            af[mt] = *reinterpret_cast<const bf16x8*>(&As[cur][row * 32 + ch * 8]);
        }
#pragma unroll
        for (int nt = 0; nt < 4; ++nt) {
            int row = wc * 64 + nt * 16 + lr;
            int ch = lk ^ ((row >> 1) & 3);
            bf[nt] = *reinterpret_cast<const bf16x8*>(&Bs[cur][row * 32 + ch * 8]);
        }
        __builtin_amdgcn_s_setprio(1);
#pragma unroll
        for (int mt = 0; mt < 2; ++mt)
#pragma unroll
            for (int nt = 0; nt < 4; ++nt)
                acc[mt][nt] = __builtin_amdgcn_mfma_f32_16x16x32_bf16(
                    af[mt], bf[nt], acc[mt][nt], 0, 0, 0);
        __builtin_amdgcn_s_setprio(0);

        if (s + 1 < ns) {
            if (s + 2 < ns)
                asm volatile("s_waitcnt vmcnt(3)" ::: "memory");
            else
                asm volatile("s_waitcnt vmcnt(0)" ::: "memory");
            __builtin_amdgcn_sched_barrier(0);
            __builtin_amdgcn_s_barrier();
            __builtin_amdgcn_sched_barrier(0);
        }
        cur = (cur == 2) ? 0 : cur + 1;
    }

    if (OUT_MODE == 4) {
        // prop1 fused: s1[b, col] = (1/64) * sum_rows relu(acc + bias)
        __shared__ float red[2][128];
        float part[4];
#pragma unroll
        for (int nt = 0; nt < 4; ++nt) {
            int col = n0 + wc * 64 + nt * 16 + lr;
            float bv = bias[col];
            float s = 0.f;
#pragma unroll
            for (int mt = 0; mt < 2; ++mt)
#pragma unroll
                for (int r = 0; r < 4; ++r) s += fmaxf(acc[mt][nt][r] + bv, 0.f);
            s += __shfl_xor(s, 16);
            s += __shfl_xor(s, 32);
            part[nt] = s;
        }
        if (lk == 0) {
#pragma unroll
            for (int nt = 0; nt < 4; ++nt) red[wr][wc * 64 + nt * 16 + lr] = part[nt];
        }
        __syncthreads();
        if (tid < 128) {
            float tot = red[0][tid] + red[1][tid];
            ((ushort*)Cout)[(size_t)blockIdx.y * 1024 + n0 + tid] =
                f2bf(tot * (1.0f / 64.0f));
        }
        return;
    }

#pragma unroll
    for (int nt = 0; nt < 4; ++nt) {
        int col = n0 + wc * 64 + nt * 16 + lr;
        if (col >= N) continue;
        float bv = (OUT_MODE == 3) ? 0.f : bias[col];
        int g = 0, dcol = 0;
        if (OUT_MODE == 2) { g = col / 34; dcol = col - g * 34; }
#pragma unroll
        for (int mt = 0; mt < 2; ++mt) {
#pragma unroll
            for (int r = 0; r < 4; ++r) {
                int row = m0 + wr * 32 + mt * 16 + lk * 4 + r;
                if (row >= M) continue;
                float v = acc[mt][nt][r] + bv;
                if (ACT == 1) v = fmaxf(v, 0.0f);
                if (OUT_MODE == 0)
                    ((float*)Cout)[(size_t)row * N + col] = v;
                else if (OUT_MODE == 1)
                    ((ushort*)Cout)[(size_t)row * N + col] = f2bf(v);
                else if (OUT_MODE == 2)
                    ((ushort*)Cout)[(size_t)row * 960 + g * 40 + dcol] = f2bf(v);
                else
                    ((float*)Cout)[(size_t)(blockIdx.y * M + row) * N + col] = v;
            }
        }
    }
}

// ---------------------------------------------------------------------------
// Fused GEMM(+bias) + residual + LayerNorm for N=272 outputs.
// Out[row,:] = LN(resid[row,:] + A[row,:]@Bt^T + bias) * lnw + lnb  (bf16,
// stride 288, cols 0..271 only). BM=64 rows/block; wave w owns rows
// w*16..w*16+15 x all 272 cols (17 MFMA tiles). 2-ring pipeline, vmcnt(0).
// ---------------------------------------------------------------------------
__global__ __launch_bounds__(256) void gemm_ln(const ushort* __restrict__ A,
                                               const ushort* __restrict__ Bt,
                                               const float* __restrict__ bias,
                                               const ushort* __restrict__ resid,
                                               const float* __restrict__ lnw,
                                               const float* __restrict__ lnb,
                                               ushort* __restrict__ Out,
                                               int K, int Kstride) {
    __shared__ ushort lds[21504];  // As: 2x2048 @0 ; Bs: 2x8704 @4096
    const int tid = threadIdx.x;
    const int m0 = blockIdx.x * 64;
    const int w = tid >> 6, lane = tid & 63;
    const int lr = lane & 15, lk = lane >> 4;
    const int ns = K >> 5;

    const int ra = w * 16 + (lane >> 2);
    const int ca = (((lane & 3) ^ ((ra >> 1) & 3)) << 3);
    const ushort* gA = &A[(size_t)(m0 + ra) * Kstride + ca];

    f32x4 acc[17];
#pragma unroll
    for (int t = 0; t < 17; ++t) acc[t] = (f32x4){0.f, 0.f, 0.f, 0.f};

    auto stage = [&](int buf, int s) {
        const int k0 = s << 5;
        __builtin_amdgcn_global_load_lds(
            (const __attribute__((address_space(1))) void*)(gA + k0),
            (__attribute__((address_space(3))) void*)(&lds[buf * 2048 + w * 512]),
            16, 0, 0);
        for (int c = w; c < 17; c += 4) {
            int row16 = c * 16 + (lane >> 2);
            int p8 = (((lane & 3) ^ ((row16 >> 1) & 3)) << 3);
            const ushort* src = &Bt[(size_t)row16 * Kstride + k0 + p8];
            __builtin_amdgcn_global_load_lds(
                (const __attribute__((address_space(1))) void*)src,
                (__attribute__((address_space(3))) void*)(&lds[4096 + buf * 8704 + c * 512]),
                16, 0, 0);
        }
    };

    stage(0, 0);
    asm volatile("s_waitcnt vmcnt(0)" ::: "memory");
    __builtin_amdgcn_sched_barrier(0);
    __builtin_amdgcn_s_barrier();
    __builtin_amdgcn_sched_barrier(0);

    int cur = 0;
    for (int s = 0; s < ns; ++s) {
        if (s + 1 < ns) stage(cur ^ 1, s + 1);

        bf16x8 af;
        {
            int row = w * 16 + lr;
            int ch = lk ^ ((row >> 1) & 3);
            af = *reinterpret_cast<const bf16x8*>(&lds[cur * 2048 + row * 32 + ch * 8]);
        }
        __builtin_amdgcn_s_setprio(1);
#pragma unroll
        for (int t = 0; t < 17; ++t) {
            int row = t * 16 + lr;
            int ch = lk ^ ((row >> 1) & 3);
            bf16x8 bf = *reinterpret_cast<const bf16x8*>(
                &lds[4096 + cur * 8704 + row * 32 + ch * 8]);
            acc[t] = __builtin_amdgcn_mfma_f32_16x16x32_bf16(af, bf, acc[t], 0, 0, 0);
        }
        __builtin_amdgcn_s_setprio(0);

        if (s + 1 < ns) {
            asm volatile("s_waitcnt vmcnt(0)" ::: "memory");
            __builtin_amdgcn_sched_barrier(0);
            __builtin_amdgcn_s_barrier();
            __builtin_amdgcn_sched_barrier(0);
        }
        cur ^= 1;
    }

    // ---- epilogue: residual + LN (rows fully in-block) ----
    __syncthreads();  // all waves done with pipeline LDS
    for (int i = tid; i < 64 * 34; i += 256) {
        int row = i / 34, c8 = i - row * 34;
        *reinterpret_cast<uint4*>(&lds[row * 272 + c8 * 8]) =
            *reinterpret_cast<const uint4*>(&resid[(size_t)(m0 + row) * D_TP + c8 * 8]);
    }
    __syncthreads();

    float sum[4] = {0.f, 0.f, 0.f, 0.f}, sq[4] = {0.f, 0.f, 0.f, 0.f};
#pragma unroll
    for (int t = 0; t < 17; ++t) {
        int col = t * 16 + lr;
        float bv = bias[col];
#pragma unroll
        for (int r = 0; r < 4; ++r) {
            int row = w * 16 + lk * 4 + r;
            float v = acc[t][r] + bv + bf2f(lds[row * 272 + col]);
            acc[t][r] = v;
            sum[r] += v;
            sq[r] += v * v;
        }
    }
#pragma unroll
    for (int mask = 1; mask <= 8; mask <<= 1)
#pragma unroll
        for (int r = 0; r < 4; ++r) {
            sum[r] += __shfl_xor(sum[r], mask);
            sq[r] += __shfl_xor(sq[r], mask);
        }
    float mu[4], inv[4];
#pragma unroll
    for (int r = 0; r < 4; ++r) {
        mu[r] = sum[r] * (1.0f / D_T);
        float var = sq[r] * (1.0f / D_T) - mu[r] * mu[r];
        inv[r] = 1.0f / sqrtf(var + 1e-5f);
    }
#pragma unroll
    for (int t = 0; t < 17; ++t) {
        int col = t * 16 + lr;
        float wv = lnw[col], bb = lnb[col];
#pragma unroll
        for (int r = 0; r < 4; ++r) {
            int row = m0 + w * 16 + lk * 4 + r;
            Out[(size_t)row * D_TP + col] = f2bf((acc[t][r] - mu[r]) * inv[r] * wv + bb);
        }
    }
}

// ---------------------------------------------------------------------------
// prop2 split-K reduce: out2[b,g] = relu(sum_ks part[ks][b][g] + bv2[g])
// ---------------------------------------------------------------------------
__global__ __launch_bounds__(256) void reduce_p2_kernel(const float* __restrict__ part,
                                                        const float* __restrict__ bv2,
                                                        float* __restrict__ out2) {
    int idx = blockIdx.x * 256 + threadIdx.x;
    if (idx >= B_DIM * F_INF) return;
    int g = idx & 1023;
    float s = bv2[g];
#pragma unroll
    for (int ks = 0; ks < 4; ++ks) s += part[(size_t)ks * B_DIM * F_INF + idx];
    out2[idx] = fmaxf(s, 0.f);
}

// ---------------------------------------------------------------------------
// seq[t,b,c] (stride 288) = c<256 ? out2 : c<272 ? PE : 0   -> bf16
// ---------------------------------------------------------------------------
__global__ void seq_kernel(const float* __restrict__ out2, const float* __restrict__ times,
                           ushort* __restrict__ seq) {
    int idx = blockIdx.x * blockDim.x + threadIdx.x;
    if (idx >= T_DIM * B_DIM * D_TP) return;
    int c = idx % D_TP;
    int tb = idx / D_TP;
    float v;
    if (c < 256) {
        v = out2[(tb % B_DIM) * 1024 + ((tb / B_DIM) << 2) + (c & 3)];
    } else if (c < 272) {
        int s = c - 256;
        int sc = (s < 8) ? s : s - 8;
        float arg = times[tb] * exp2f(-8.0f * (float)sc * (1.0f / 7.0f));
        v = (s < 8) ? sinf(arg) : cosf(arg);
    } else {
        v = 0.f;
    }
    seq[idx] = f2bf(v);
}

// ---------------------------------------------------------------------------
// MFMA flash attention (validated round 6; attno stride 288).
// ---------------------------------------------------------------------------
__global__ __launch_bounds__(256) void attn_mfma(const ushort* __restrict__ qkv,
                                                 const int* __restrict__ lengths,
                                                 ushort* __restrict__ attno) {
    const int b = blockIdx.x >> 3;
    const int h = blockIdx.x & 7;
    const int tid = threadIdx.x;
    const int w = tid >> 6, lane = tid & 63;
    const int lr = lane & 15, lk = lane >> 4;
    __shared__ ushort Ks[2][64 * 40];
    __shared__ ushort Vt[2][48 * 72];
    __shared__ ushort Ps[4][64 * 72];
    const int len = lengths[b];
    const float scale = 0.1714985851f;  // 1/sqrt(34)
    const bf16x8 zv = {0, 0, 0, 0, 0, 0, 0, 0};

    for (int i = tid; i < 2 * 8 * 72; i += 256) {
        int bb = i / 576;
        Vt[bb][40 * 72 + (i - bb * 576)] = 0;
    }

    const int srow0 = tid / 5, sch0 = tid - srow0 * 5;
    const int srow1 = (tid + 256) / 5, sch1 = (tid + 256) - srow1 * 5;
    const int sjp0 = (srow0 & 15) * 4 + (srow0 >> 4);
    const int sjp1 = (srow1 & 15) * 4 + (srow1 >> 4);
    const bool has1 = (tid < 64);
    bf16x8 kreg0, kreg1, vreg0, vreg1;

    auto LOADS = [&](int c) {
        const ushort* b0 = &qkv[(size_t)((c * 64 + srow0) * 32 + b) * 960 + h * 40];
        kreg0 = *reinterpret_cast<const bf16x8*>(b0 + 320 + sch0 * 8);
        vreg0 = *reinterpret_cast<const bf16x8*>(b0 + 640 + sch0 * 8);
        if (has1) {
            const ushort* b1 = &qkv[(size_t)((c * 64 + srow1) * 32 + b) * 960 + h * 40];
            kreg1 = *reinterpret_cast<const bf16x8*>(b1 + 320 + sch1 * 8);
            vreg1 = *reinterpret_cast<const bf16x8*>(b1 + 640 + sch1 * 8);
        }
    };
    auto WRITES = [&](int buf) {
        *reinterpret_cast<bf16x8*>(&Ks[buf][srow0 * 40 + sch0 * 8]) = kreg0;
#pragma unroll
        for (int e = 0; e < 8; ++e) Vt[buf][(sch0 * 8 + e) * 72 + sjp0] = (ushort)vreg0[e];
        if (has1) {
            *reinterpret_cast<bf16x8*>(&Ks[buf][srow1 * 40 + sch1 * 8]) = kreg1;
#pragma unroll
            for (int e = 0; e < 8; ++e) Vt[buf][(sch1 * 8 + e) * 72 + sjp1] = (ushort)vreg1[e];
        }
    };

    bf16x8 qf0[4], qf1[4];
#pragma unroll
    for (int it = 0; it < 4; ++it) {
        int t = w * 64 + it * 16 + lr;
        const ushort* qrow = &qkv[(size_t)(t * 32 + b) * 960 + h * 40];
        qf0[it] = *reinterpret_cast<const bf16x8*>(qrow + lk * 8);
        qf1[it] = (lk == 0) ? *reinterpret_cast<const bf16x8*>(qrow + 32) : zv;
    }

    f32x4 oacc[4][3];
#pragma unroll
    for (int it = 0; it < 4; ++it)
#pragma unroll
        for (int dt = 0; dt < 3; ++dt) oacc[it][dt] = (f32x4){0.f, 0.f, 0.f, 0.f};
    float m[4][4], l[4][4];
#pragma unroll
    for (int it = 0; it < 4; ++it)
#pragma unroll
        for (int r = 0; r < 4; ++r) { m[it][r] = -1e30f; l[it][r] = 0.f; }

    const int nchunks = (len + 63) >> 6;
    LOADS(0);
    WRITES(0);
    __syncthreads();

    int cur = 0;
    for (int c = 0; c < nchunks; ++c) {
        const bool pre = (c + 1 < nchunks);
        if (pre) LOADS(c + 1);

        bf16x8 kf0[4], kf1[4];
#pragma unroll
        for (int jt = 0; jt < 4; ++jt) {
            int j = jt * 16 + lr;
            kf0[jt] = *reinterpret_cast<const bf16x8*>(&Ks[cur][j * 40 + lk * 8]);
            kf1[jt] = (lk == 0) ? *reinterpret_cast<const bf16x8*>(&Ks[cur][j * 40 + 32]) : zv;
        }

        const bool tail = (c * 64 + 64 > len);
#pragma unroll
        for (int it = 0; it < 4; ++it) {
            f32x4 sacc[4];
#pragma unroll
            for (int jt = 0; jt < 4; ++jt) sacc[jt] = (f32x4){0.f, 0.f, 0.f, 0.f};
            __builtin_amdgcn_s_setprio(1);
#pragma unroll
            for (int jt = 0; jt < 4; ++jt) {
                sacc[jt] = __builtin_amdgcn_mfma_f32_16x16x32_bf16(qf0[it], kf0[jt],
                                                                   sacc[jt], 0, 0, 0);
                sacc[jt] = __builtin_amdgcn_mfma_f32_16x16x32_bf16(qf1[it], kf1[jt],
                                                                   sacc[jt], 0, 0, 0);
            }
            __builtin_amdgcn_s_setprio(0);
            float cm[4] = {-1e30f, -1e30f, -1e30f, -1e30f};
#pragma unroll
            for (int jt = 0; jt < 4; ++jt) {
                bool dead = tail && (c * 64 + jt * 16 + lr >= len);
#pragma unroll
                for (int r = 0; r < 4; ++r) {
                    float sv = dead ? -1e30f : sacc[jt][r];
                    sacc[jt][r] = sv;
                    cm[r] = fmaxf(cm[r], sv);
                }
            }
#pragma unroll
            for (int mask = 1; mask <= 8; mask <<= 1)
#pragma unroll
                for (int r = 0; r < 4; ++r) cm[r] = fmaxf(cm[r], __shfl_xor(cm[r], mask));
#pragma unroll
            for (int r = 0; r < 4; ++r) {
                float mn = fmaxf(m[it][r], cm[r]);
                float corr = __expf((m[it][r] - mn) * scale);
                m[it][r] = mn;
                l[it][r] *= corr;
#pragma unroll
                for (int dt = 0; dt < 3; ++dt) oacc[it][dt][r] *= corr;
            }
            float ls[4] = {0.f, 0.f, 0.f, 0.f};
#pragma unroll
            for (int jt = 0; jt < 4; ++jt)
#pragma unroll
                for (int r = 0; r < 4; ++r) {
                    float e = __expf((sacc[jt][r] - m[it][r]) * scale);
                    sacc[jt][r] = e;
                    ls[r] += e;
                }
#pragma unroll
            for (int mask = 1; mask <= 8; mask <<= 1)
#pragma unroll
                for (int r = 0; r < 4; ++r) ls[r] += __shfl_xor(ls[r], mask);
#pragma unroll
            for (int r = 0; r < 4; ++r) l[it][r] += ls[r];
#pragma unroll
            for (int r = 0; r < 4; ++r) {
                int i = it * 16 + lk * 4 + r;
                uint u0 = (uint)f2bf(sacc[0][r]) | ((uint)f2bf(sacc[1][r]) << 16);
                uint u1 = (uint)f2bf(sacc[2][r]) | ((uint)f2bf(sacc[3][r]) << 16);
                uint2 pk = make_uint2(u0, u1);
                *reinterpret_cast<uint2*>(&Ps[w][i * 72 + lr * 4]) = pk;
            }
        }

        bf16x8 vf[3][2], pf[4][2];
#pragma unroll
        for (int dt = 0; dt < 3; ++dt)
#pragma unroll
            for (int ks = 0; ks < 2; ++ks)
                vf[dt][ks] = *reinterpret_cast<const bf16x8*>(
                    &Vt[cur][(dt * 16 + lr) * 72 + ks * 32 + lk * 8]);
#pragma unroll
        for (int it = 0; it < 4; ++it)
#pragma unroll
            for (int ks = 0; ks < 2; ++ks)
                pf[it][ks] = *reinterpret_cast<const bf16x8*>(
                    &Ps[w][(it * 16 + lr) * 72 + ks * 32 + lk * 8]);
        __builtin_amdgcn_s_setprio(1);
#pragma unroll
        for (int it = 0; it < 4; ++it)
#pragma unroll
            for (int dt = 0; dt < 3; ++dt)
#pragma unroll
                for (int ks = 0; ks < 2; ++ks)
                    oacc[it][dt] = __builtin_amdgcn_mfma_f32_16x16x32_bf16(
                        pf[it][ks], vf[dt][ks], oacc[it][dt], 0, 0, 0);
        __builtin_amdgcn_s_setprio(0);

        if (pre) WRITES(cur ^ 1);
        __syncthreads();
        cur ^= 1;
    }

#pragma unroll
    for (int it = 0; it < 4; ++it)
#pragma unroll
        for (int r = 0; r < 4; ++r) {
            float inv = 1.0f / l[it][r];
            int t = w * 64 + it * 16 + lk * 4 + r;
            ushort* orow = &attno[(size_t)(t * 32 + b) * D_TP + h * 34];
#pragma unroll
            for (int dt = 0; dt < 3; ++dt) {
                int d = dt * 16 + lr;
                if (d < 34) orow[d] = f2bf(oacc[it][dt][r] * inv);
            }
        }
}

// ---------------------------------------------------------------------------
// pool stage 1: partial[chunk][b][272] over 32 t-rows (seq stride 288).
// ---------------------------------------------------------------------------
__global__ __launch_bounds__(256) void pool_partial(const ushort* __restrict__ seq,
                                                    const int* __restrict__ lengths,
                                                    float* __restrict__ partial) {
    const int chunk = blockIdx.x;
    const int b = blockIdx.y;
    const int tid = threadIdx.x;
    if (tid >= 136) return;
    const int len = lengths[b];
    float s0 = 0.f, s1 = 0.f;
    int t0 = chunk * 32;
    int tmax = len - t0;
    if (tmax > 32) tmax = 32;
#pragma unroll 4
    for (int r = 0; r < tmax; ++r) {
        uint u = *reinterpret_cast<const uint*>(
            &seq[(size_t)((t0 + r) * B_DIM + b) * D_TP + tid * 2]);
        s0 += __uint_as_float(u << 16);
        s1 += __uint_as_float(u & 0xffff0000u);
    }
    float* p = &partial[(size_t)(chunk * B_DIM + b) * D_T + tid * 2];
    p[0] = s0;
    p[1] = s1;
}

// ---------------------------------------------------------------------------
// head: agg = (sum partials)/(len+1); hid = relu(agg@w1+b1);
// logits = hid@w2+b2; softmax. One block per b.
// ---------------------------------------------------------------------------
__global__ __launch_bounds__(256) void head_kernel(const float* __restrict__ partial,
                                                   const int* __restrict__ lengths,
                                                   const float* __restrict__ w1,
                                                   const float* __restrict__ b1,
                                                   const float* __restrict__ w2,
                                                   const float* __restrict__ b2,
                                                   float* __restrict__ out) {
    const int b = blockIdx.x;
    const int tid = threadIdx.x;
    const int len = lengths[b];
    __shared__ float agg_s[D_T];
    __shared__ float hid[D_T];
    float inv = 1.0f / (float)(len + 1);
    for (int c = tid; c < D_T; c += 256) {
        float s = 0.f;
#pragma unroll
        for (int ch = 0; ch < 8; ++ch)
            s += partial[(size_t)(ch * B_DIM + b) * D_T + c];
        agg_s[c] = s * inv;
    }
    __syncthreads();
    for (int j = tid; j < D_T; j += 256) {
        float acc = b1[j];
        for (int k = 0; k < D_T; ++k) acc += agg_s[k] * w1[k * D_T + j];
        hid[j] = fmaxf(acc, 0.f);
    }
    __syncthreads();
    if (tid < 64) {
        float l0 = 0.f, l1 = 0.f;
        for (int k = tid; k < D_T; k += 64) {
            float hv = hid[k];
            l0 += hv * w2[k * 2 + 0];
            l1 += hv * w2[k * 2 + 1];
        }
#pragma unroll
        for (int off = 32; off; off >>= 1) {
            l0 += __shfl_down(l0, off);
            l1 += __shfl_down(l1, off);
        }
        if (tid == 0) {
            l0 += b2[0];
            l1 += b2[1];
            float mx = fmaxf(l0, l1);
            float e0 = expf(l0 - mx), e1 = expf(l1 - mx);
            float nrm = 1.0f / (e0 + e1);
            out[b * 2 + 0] = e0 * nrm;
            out[b * 2 + 1] = e1 * nrm;
        }
    }
}

// ---------------------------------------------------------------------------
extern "C" void kernel_launch(void* const* d_in, const int* in_sizes, int n_in,
                              void* d_out, int out_size, void* d_ws, size_t ws_size,
                              hipStream_t stream) {
    const float* x      = (const float*)d_in[0];
    const float* times  = (const float*)d_in[1];
    const int*   lens   = (const int*)d_in[2];
    const float* R_u    = (const float*)d_in[3];
    const float* Wv1    = (const float*)d_in[4];
    const float* bv1    = (const float*)d_in[5];
    const float* Wv2    = (const float*)d_in[6];
    const float* bv2    = (const float*)d_in[7];
    const float* qkv_w  = (const float*)d_in[8];
    const float* qkv_b  = (const float*)d_in[9];
    const float* out_w  = (const float*)d_in[10];
    const float* out_b  = (const float*)d_in[11];
    const float* ln1_w  = (const float*)d_in[12];
    const float* ln1_b  = (const float*)d_in[13];
    const float* ln2_w  = (const float*)d_in[14];
    const float* ln2_b  = (const float*)d_in[15];
    const float* ffn_w1 = (const float*)d_in[16];
    const float* ffn_b1 = (const float*)d_in[17];
    const float* ffn_w2 = (const float*)d_in[18];
    const float* ffn_b2 = (const float*)d_in[19];
    const float* mlp_w1 = (const float*)d_in[20];
    const float* mlp_b1 = (const float*)d_in[21];
    const float* mlp_w2 = (const float*)d_in[22];
    const float* mlp_b2 = (const float*)d_in[23];
    float* outp = (float*)d_out;

    char* base = (char*)d_ws;
    size_t used = 0;
    auto alloc = [&](size_t bytes) -> char* {
        char* p = base + used;
        used += (bytes + 255) & ~(size_t)255;
        return p;
    };
    const int TB = T_DIM * B_DIM;  // 8192

    ushort* xn    = (ushort*)alloc((size_t)2048 * 1024 * 2);
    ushort* s1    = (ushort*)alloc((size_t)32 * 1024 * 2);
    float*  p2p   = (float*) alloc((size_t)4 * 32 * 1024 * 4);
    float*  out2  = (float*) alloc((size_t)32 * 1024 * 4);
    ushort* seq   = (ushort*)alloc((size_t)TB * D_TP * 2);
    ushort* qkvb  = (ushort*)alloc((size_t)TB * 960 * 2);
    ushort* attno = (ushort*)alloc((size_t)TB * D_TP * 2);
    ushort* x1    = (ushort*)alloc((size_t)TB * D_TP * 2);
    ushort* h1    = (ushort*)alloc((size_t)TB * DFF_DIM * 2);
    float*  ppart = (float*) alloc((size_t)8 * B_DIM * D_T * 4);
    ushort* wv1t  = (ushort*)alloc((size_t)1024 * 1024 * 2);
    ushort* wv2t  = (ushort*)alloc((size_t)1024 * 1024 * 2);
    ushort* qkvwt[2]; ushort* outwt[2]; ushort* f1wt[2]; ushort* f2wt[2];
    for (int l = 0; l < 2; ++l) {
        qkvwt[l] = (ushort*)alloc((size_t)816 * D_TP * 2);
        outwt[l] = (ushort*)alloc((size_t)272 * D_TP * 2);
        f1wt[l]  = (ushort*)alloc((size_t)1024 * D_TP * 2);
        f2wt[l]  = (ushort*)alloc((size_t)272 * 1024 * 2);
    }
    if (used > ws_size) return;

    // ---- weight convert+transpose ----
    {
        WT segs;
        const float* srcs[10] = {Wv1, Wv2,
                                 qkv_w, out_w, ffn_w1, ffn_w2,
                                 qkv_w + (size_t)272 * 816, out_w + (size_t)272 * 272,
                                 ffn_w1 + (size_t)272 * 1024, ffn_w2 + (size_t)1024 * 272};
        ushort* dsts[10] = {wv1t, wv2t, qkvwt[0], outwt[0], f1wt[0], f2wt[0],
                            qkvwt[1], outwt[1], f1wt[1], f2wt[1]};
        int Ksz[10] = {1024, 1024, 272, 272, 272, 1024, 272, 272, 272, 1024};
        int Nsz[10] = {1024, 1024, 816, 272, 1024, 272, 816, 272, 1024, 272};
        int Kpd[10] = {1024, 1024, D_TP, D_TP, D_TP, 1024, D_TP, D_TP, D_TP, 1024};
        int acc = 0;
        for (int i = 0; i < 10; ++i) {
            segs.tstart[i] = acc;
            segs.src[i] = srcs[i];
            segs.dst[i] = dsts[i];
            segs.K[i] = Ksz[i];
            segs.N[i] = Nsz[i];
            segs.Kp[i] = Kpd[i];
            segs.ntn[i] = Nsz[i] / 16;
            acc += (Ksz[i] / 16) * (Nsz[i] / 16);
        }
        segs.tstart[10] = acc;
        wconv_tiled<<<acc, 256, 0, stream>>>(segs);
    }

    // ---- merged init: xn elementwise + all pad zeroing ----
    {
        PadPtrs pp;
        pp.wt[0] = (uint*)qkvwt[0]; pp.nrows[0] = 816;
        pp.wt[1] = (uint*)qkvwt[1]; pp.nrows[1] = 816;
        pp.wt[2] = (uint*)outwt[0]; pp.nrows[2] = 272;
        pp.wt[3] = (uint*)outwt[1]; pp.nrows[3] = 272;
        pp.wt[4] = (uint*)f1wt[0];  pp.nrows[4] = 1024;
        pp.wt[5] = (uint*)f1wt[1];  pp.nrows[5] = 1024;
        int n = B_DIM * N_DIM * F_INF + TB * 8 + TB * 72 +
                (816 + 816 + 272 + 272 + 1024 + 1024) * 8;
        init_kernel<<<(n + 255) / 256, 256, 0, stream>>>(x, R_u, xn, (uint*)qkvb,
                                                         (uint*)x1, (uint*)attno, pp);
    }

    // prop1 fused: [2048,1024]@[1024,1024] + relu + row-mean -> s1 [32][1024]
    gemm_mfma<1, 4><<<dim3(8, 32), 256, 0, stream>>>(xn, wv1t, bv1, s1,
                                                     2048, 1024, 1024, 1024);
    // prop2 split-K x4
    gemm_mfma<0, 3><<<dim3(8, 4), 256, 0, stream>>>(s1, wv2t, nullptr, p2p,
                                                    32, 1024, 256, 1024);
    reduce_p2_kernel<<<128, 256, 0, stream>>>(p2p, bv2, out2);

    {
        int n = TB * D_TP;
        seq_kernel<<<(n + 255) / 256, 256, 0, stream>>>(out2, times, seq);
    }

    for (int l = 0; l < 2; ++l) {
        const float* qb  = qkv_b + (size_t)l * 816;
        const float* ob  = out_b + (size_t)l * D_T;
        const float* l1w = ln1_w + (size_t)l * D_T;
        const float* l1b = ln1_b + (size_t)l * D_T;
        const float* l2w = ln2_w + (size_t)l * D_T;
        const float* l2b = ln2_b + (size_t)l * D_T;
        const float* f1b = ffn_b1 + (size_t)l * DFF_DIM;
        const float* f2b = ffn_b2 + (size_t)l * D_T;

        // QKV: [8192,288]@[288,816] -> bf16 head-padded
        gemm_mfma<0, 2><<<dim3(7, 128), 256, 0, stream>>>(seq, qkvwt[l], qb, qkvb,
                                                          TB, 816, D_TP, D_TP);
        attn_mfma<<<B_DIM * H_DIM, 256, 0, stream>>>(qkvb, lens, attno);
        // out-proj + resid(seq) + LN1 -> x1
        gemm_ln<<<128, 256, 0, stream>>>(attno, outwt[l], ob, seq, l1w, l1b, x1,
                                         D_TP, D_TP);
        // FFN1: relu([8192,288]@[288,1024]) -> bf16
        gemm_mfma<1, 1><<<dim3(8, 128), 256, 0, stream>>>(x1, f1wt[l], f1b, h1,
                                                          TB, DFF_DIM, D_TP, D_TP);
        // FFN2 + resid(x1) + LN2 -> seq
        gemm_ln<<<128, 256, 0, stream>>>(h1, f2wt[l], f2b, x1, l2w, l2b, seq,
                                         1024, 1024);
    }

    pool_partial<<<dim3(8, B_DIM), 256, 0, stream>>>(seq, lens, ppart);
    head_kernel<<<B_DIM, 256, 0, stream>>>(ppart, lens, mlp_w1, mlp_b1,
                                           mlp_w2, mlp_b2, outp);
}